// Round 1
// baseline (2383.107 us; speedup 1.0000x reference)
//
#include <hip/hip_runtime.h>
#include <stdint.h>

#define BATCH 32
#define HWD 224
#define PATCH 16
#define HP 14
#define NP (BATCH * HP * HP)   // 6272 patches
#define DIM 768
#define EMB 768
#define K0 512
#define K1 2048
#define K2 8192

#define MT 32    // patches per block tile
#define NT 256   // centers per chunk (== blockDim)
#define DT 64    // d-dim chunk

typedef unsigned long long ull;

__device__ __forceinline__ unsigned int fkey(float f) {
    unsigned int u = __float_as_uint(f);
    return (u & 0x80000000u) ? ~u : (u | 0x80000000u);  // monotone fp32 -> u32
}

// ---------------- patchify: data[b,3,224,224] -> x[p=6272][d=768] ----------------
__global__ void patchify_kernel(const float* __restrict__ data, float* __restrict__ x) {
    int gid = blockIdx.x * 256 + threadIdx.x;   // grid covers NP*DIM exactly
    int d = gid % DIM;
    int p = gid / DIM;
    int b = p / 196; int t = p % 196; int i = t / 14, j = t % 14;
    int ch = d >> 8; int r = d & 255; int py = r >> 4; int px = r & 15;
    x[gid] = data[((b * 3 + ch) * HWD + i * PATCH + py) * HWD + j * PATCH + px];
}

// ---------------- center row norms ----------------
__global__ void norms_kernel(const float* __restrict__ c, float* __restrict__ nrm) {
    int k = blockIdx.x;
    const float* row = c + (size_t)k * DIM;
    float s = 0.f;
    for (int d = threadIdx.x; d < DIM; d += 64) { float v = row[d]; s += v * v; }
    #pragma unroll
    for (int off = 32; off; off >>= 1) s += __shfl_down(s, off, 64);
    if (threadIdx.x == 0) nrm[k] = s;
}

__global__ void init_slots_kernel(ull* __restrict__ slots) {
    int i = blockIdx.x * 256 + threadIdx.x;
    if (i < NP) slots[i] = 0xFFFFFFFFFFFFFFFFull;
}

// ---------------- classify: argmin_k ||v_p - c_k||^2 (as ||c||^2 - 2 v.c) ----------------
// grid: (NP/MT, kSplit); block 256. Transposed LDS tiles: conflict-free float4 compute reads.
__global__ __launch_bounds__(256, 2) void classify_kernel(
    const float* __restrict__ v, const float* __restrict__ cent,
    const float* __restrict__ cnorm, int kCount,
    ull* __restrict__ slots)
{
    __shared__ __align__(16) float cs[DT][NT];  // 64 KB  (declare first: small ds offsets)
    __shared__ __align__(16) float xs[DT][MT];  // 8 KB
    const int pbase = blockIdx.x * MT;
    const int kBase = blockIdx.y * kCount;
    const int tid = threadIdx.x;
    const int tm = tid >> 5;   // 0..7  -> m rows tm*4 .. tm*4+3
    const int tn = tid & 31;   // 0..31 -> n cols tn*8 .. tn*8+7

    float best[4];
    int bidx[4];
    #pragma unroll
    for (int mi = 0; mi < 4; ++mi) { best[mi] = 3.4e38f; bidx[mi] = 0; }

    for (int nc = 0; nc < kCount; nc += NT) {
        float acc[4][8];
        #pragma unroll
        for (int mi = 0; mi < 4; ++mi)
            #pragma unroll
            for (int ni = 0; ni < 8; ++ni) acc[mi][ni] = 0.f;

        for (int dc = 0; dc < DIM; dc += DT) {
            // stage x tile transposed: xs[d][m]
            {
                int m = tid >> 3, d0 = (tid & 7) * 8;
                const float* src = v + (size_t)(pbase + m) * DIM + dc + d0;
                float4 a = *(const float4*)src;
                float4 b4 = *(const float4*)(src + 4);
                xs[d0 + 0][m] = a.x;  xs[d0 + 1][m] = a.y;
                xs[d0 + 2][m] = a.z;  xs[d0 + 3][m] = a.w;
                xs[d0 + 4][m] = b4.x; xs[d0 + 5][m] = b4.y;
                xs[d0 + 6][m] = b4.z; xs[d0 + 7][m] = b4.w;
            }
            // stage c tile transposed: cs[d][n]; thread tid owns center row kBase+nc+tid
            {
                const float* src = cent + (size_t)(kBase + nc + tid) * DIM + dc;
                #pragma unroll
                for (int q = 0; q < 16; ++q) {
                    float4 a = *(const float4*)(src + q * 4);
                    cs[q * 4 + 0][tid] = a.x; cs[q * 4 + 1][tid] = a.y;
                    cs[q * 4 + 2][tid] = a.z; cs[q * 4 + 3][tid] = a.w;
                }
            }
            __syncthreads();
            #pragma unroll 16
            for (int d = 0; d < DT; ++d) {
                const float4 xv = *(const float4*)(&xs[d][tm * 4]);
                const float4 ca = *(const float4*)(&cs[d][tn * 8]);
                const float4 cb = *(const float4*)(&cs[d][tn * 8 + 4]);
                const float xm[4] = {xv.x, xv.y, xv.z, xv.w};
                const float cn[8] = {ca.x, ca.y, ca.z, ca.w, cb.x, cb.y, cb.z, cb.w};
                #pragma unroll
                for (int mi = 0; mi < 4; ++mi)
                    #pragma unroll
                    for (int ni = 0; ni < 8; ++ni)
                        acc[mi][ni] = fmaf(xm[mi], cn[ni], acc[mi][ni]);
            }
            __syncthreads();
        }
        // scores + running argmin (k ascending, strict < => lowest-index ties like np.argmin)
        #pragma unroll
        for (int ni = 0; ni < 8; ++ni) {
            int k = kBase + nc + tn * 8 + ni;
            float nor = cnorm[k];
            #pragma unroll
            for (int mi = 0; mi < 4; ++mi) {
                float s = fmaf(-2.f, acc[mi][ni], nor);
                if (s < best[mi]) { best[mi] = s; bidx[mi] = k; }
            }
        }
    }
    // reduce across the 32 tn threads (half-wave), then atomicMin across blocks
    #pragma unroll
    for (int mi = 0; mi < 4; ++mi) {
        ull pk = ((ull)fkey(best[mi]) << 32) | (unsigned int)bidx[mi];
        #pragma unroll
        for (int off = 16; off; off >>= 1) {
            ull o = __shfl_xor(pk, off, 32);
            if (o < pk) pk = o;
        }
        if (tn == 0) atomicMin(&slots[pbase + tm * 4 + mi], pk);
    }
}

// ---------------- update: v -= c[cls];  store cls ----------------
__global__ void update_kernel(float* __restrict__ v, const float* __restrict__ cent,
                              const ull* __restrict__ slots, int* __restrict__ cls) {
    int gid = blockIdx.x * 256 + threadIdx.x;
    int p = gid / DIM, d = gid % DIM;
    int idx = (int)(slots[p] & 0xFFFFFFFFull);
    v[gid] -= cent[(size_t)idx * DIM + d];
    if (d == 0) cls[p] = idx;
}

// ---------------- finalize: embed / img_sum / diff_out with layout transposes ----------------
__global__ void finalize_kernel(const float* __restrict__ vdiff,
    const int* __restrict__ cls0, const int* __restrict__ cls1, const int* __restrict__ cls2,
    const float* __restrict__ c0, const float* __restrict__ c1, const float* __restrict__ c2,
    const float* __restrict__ e0, const float* __restrict__ e1, const float* __restrict__ e2,
    float* __restrict__ out)
{
    int p = blockIdx.x;
    int b = p / 196, t = p % 196, i = t / 14, j = t % 14;
    int i0 = cls0[p], i1 = cls1[p], i2 = cls2[p];
    float* out_embed = out;
    float* out_img   = out + (size_t)NP * DIM;
    float* out_diff  = out + 2 * (size_t)NP * DIM;
    for (int d = threadIdx.x; d < DIM; d += 256) {
        float ev = e0[(size_t)i0 * EMB + d] + e1[(size_t)i1 * EMB + d] + e2[(size_t)i2 * EMB + d];
        out_embed[((b * EMB + d) * HP + i) * HP + j] = ev;

        float iv = c0[(size_t)i0 * DIM + d] + c1[(size_t)i1 * DIM + d] + c2[(size_t)i2 * DIM + d];
        int ch = d >> 8, r = d & 255, py = r >> 4, px = r & 15;
        out_img[((b * 3 + ch) * HWD + i * PATCH + py) * HWD + j * PATCH + px] = iv;

        out_diff[((b * DIM + d) * HP + i) * HP + j] = vdiff[(size_t)p * DIM + d];
    }
}

extern "C" void kernel_launch(void* const* d_in, const int* in_sizes, int n_in,
                              void* d_out, int out_size, void* d_ws, size_t ws_size,
                              hipStream_t stream) {
    const float* data = (const float*)d_in[0];
    const float* c0 = (const float*)d_in[1];
    const float* c1 = (const float*)d_in[2];
    const float* c2 = (const float*)d_in[3];
    const float* e0 = (const float*)d_in[4];
    const float* e1 = (const float*)d_in[5];
    const float* e2 = (const float*)d_in[6];
    float* out = (float*)d_out;

    char* w = (char*)d_ws;
    float* xbuf = (float*)w;            w += (size_t)NP * DIM * 4;   // 19.27 MB
    ull* slots = (ull*)w;               w += (size_t)NP * 8;
    int* cls0 = (int*)w;                w += (size_t)NP * 4;
    int* cls1 = (int*)w;                w += (size_t)NP * 4;
    int* cls2 = (int*)w;                w += (size_t)NP * 4;
    float* nrm0 = (float*)w;            w += (size_t)K0 * 4;
    float* nrm1 = (float*)w;            w += (size_t)K1 * 4;
    float* nrm2 = (float*)w;            w += (size_t)K2 * 4;

    const int ELEM_BLOCKS = (NP * DIM) / 256;   // 18816

    patchify_kernel<<<ELEM_BLOCKS, 256, 0, stream>>>(data, xbuf);
    norms_kernel<<<K0, 64, 0, stream>>>(c0, nrm0);
    norms_kernel<<<K1, 64, 0, stream>>>(c1, nrm1);
    norms_kernel<<<K2, 64, 0, stream>>>(c2, nrm2);

    // level 0: K=512, split 2 -> kCount=256 (1 chunk of NT)
    init_slots_kernel<<<(NP + 255) / 256, 256, 0, stream>>>(slots);
    classify_kernel<<<dim3(NP / MT, 2), 256, 0, stream>>>(xbuf, c0, nrm0, K0 / 2, slots);
    update_kernel<<<ELEM_BLOCKS, 256, 0, stream>>>(xbuf, c0, slots, cls0);

    // level 1: K=2048, split 2 -> kCount=1024
    init_slots_kernel<<<(NP + 255) / 256, 256, 0, stream>>>(slots);
    classify_kernel<<<dim3(NP / MT, 2), 256, 0, stream>>>(xbuf, c1, nrm1, K1 / 2, slots);
    update_kernel<<<ELEM_BLOCKS, 256, 0, stream>>>(xbuf, c1, slots, cls1);

    // level 2: K=8192, split 2 -> kCount=4096
    init_slots_kernel<<<(NP + 255) / 256, 256, 0, stream>>>(slots);
    classify_kernel<<<dim3(NP / MT, 2), 256, 0, stream>>>(xbuf, c2, nrm2, K2 / 2, slots);
    update_kernel<<<ELEM_BLOCKS, 256, 0, stream>>>(xbuf, c2, slots, cls2);

    finalize_kernel<<<NP, 256, 0, stream>>>(xbuf, cls0, cls1, cls2,
                                            c0, c1, c2, e0, e1, e2, out);
}